// Round 1
// baseline (6696.517 us; speedup 1.0000x reference)
//
#include <hip/hip_runtime.h>
#include <hip/hip_bf16.h>

#define NUSER 100000
#define NGAME 20000
#define HDIM  128

// ---------------------------------------------------------------------------
// proj: out[r][c] = relu(b[c] + sum_k x[r][k] * W[k][c]),  W row-major [K][H]
// one thread per output element; wave = 64 consecutive c of one row
// ---------------------------------------------------------------------------
template <int K>
__global__ __launch_bounds__(256) void proj_kernel(
    const float* __restrict__ x, const float* __restrict__ W,
    const float* __restrict__ b, float* __restrict__ out, int n_rows) {
  int i = blockIdx.x * blockDim.x + threadIdx.x;
  if (i >= n_rows * HDIM) return;
  int r = i >> 7;
  int c = i & (HDIM - 1);
  const float* xr = x + (size_t)r * K;
  float acc = b[c];
#pragma unroll
  for (int k = 0; k < K; ++k) acc = fmaf(xr[k], W[k * HDIM + c], acc);
  out[i] = fmaxf(acc, 0.0f);
}

// ---------------------------------------------------------------------------
// scatter: for each edge e: sum[dst[e]][:] += feat[src[e]][:]; cnt[dst[e]] += 1
// 32 lanes per edge, float4 per lane
// ---------------------------------------------------------------------------
__global__ __launch_bounds__(256) void scatter_kernel(
    const float* __restrict__ feat, const int* __restrict__ src,
    const int* __restrict__ dst, float* __restrict__ sum,
    float* __restrict__ cnt, int nE) {
  int t = blockIdx.x * blockDim.x + threadIdx.x;
  int e = t >> 5;
  int lane = t & 31;
  if (e >= nE) return;
  int s = src[e];
  int d = dst[e];
  const float4 v = *reinterpret_cast<const float4*>(feat + (size_t)s * HDIM + lane * 4);
  float* p = sum + (size_t)d * HDIM + lane * 4;
  atomicAdd(p + 0, v.x);
  atomicAdd(p + 1, v.y);
  atomicAdd(p + 2, v.z);
  atomicAdd(p + 3, v.w);
  if (lane == 0) atomicAdd(cnt + d, 1.0f);
}

// ---------------------------------------------------------------------------
// out: out[r][c] = bl[c] + (sum[r][:] / max(cnt[r],1)) . Wl[:][c] + h[r][:] . Wr[:][c]
// ---------------------------------------------------------------------------
__global__ __launch_bounds__(256) void out_kernel(
    const float* __restrict__ seg_sum, const float* __restrict__ cnt,
    const float* __restrict__ h, const float* __restrict__ Wl,
    const float* __restrict__ bl, const float* __restrict__ Wr,
    float* __restrict__ out, int n_rows) {
  int i = blockIdx.x * blockDim.x + threadIdx.x;
  if (i >= n_rows * HDIM) return;
  int r = i >> 7;
  int c = i & (HDIM - 1);
  float inv = 1.0f / fmaxf(cnt[r], 1.0f);
  const float* mr = seg_sum + (size_t)r * HDIM;
  const float* hr = h + (size_t)r * HDIM;
  float acc_m = 0.0f;
  float acc_h = 0.0f;
#pragma unroll
  for (int k = 0; k < HDIM; ++k) {
    acc_m = fmaf(mr[k], Wl[k * HDIM + c], acc_m);
    acc_h = fmaf(hr[k], Wr[k * HDIM + c], acc_h);
  }
  out[i] = bl[c] + inv * acc_m + acc_h;
}

extern "C" void kernel_launch(void* const* d_in, const int* in_sizes, int n_in,
                              void* d_out, int out_size, void* d_ws, size_t ws_size,
                              hipStream_t stream) {
  const float* x_user = (const float*)d_in[0];
  const float* x_game = (const float*)d_in[1];
  const float* W_user = (const float*)d_in[2];
  const float* b_user = (const float*)d_in[3];
  const float* W_game = (const float*)d_in[4];
  const float* b_game = (const float*)d_in[5];
  const float* Wl_ug  = (const float*)d_in[6];
  const float* bl_ug  = (const float*)d_in[7];
  const float* Wr_ug  = (const float*)d_in[8];
  const float* Wl_gu  = (const float*)d_in[9];
  const float* bl_gu  = (const float*)d_in[10];
  const float* Wr_gu  = (const float*)d_in[11];
  const int*   src_ug = (const int*)d_in[12];
  const int*   dst_ug = (const int*)d_in[13];
  const int*   src_gu = (const int*)d_in[14];
  const int*   dst_gu = (const int*)d_in[15];
  const int E = in_sizes[12];

  // workspace carve (f32 elements), 256B aligned chunks
  char* ws = (char*)d_ws;
  float* hu    = (float*)ws;                 ws += (size_t)NUSER * HDIM * 4;   // 51.2 MB
  float* hg    = (float*)ws;                 ws += (size_t)NGAME * HDIM * 4;   // 10.2 MB
  float* sum_g = (float*)ws;                 ws += (size_t)NGAME * HDIM * 4;   // 10.2 MB
  float* sum_u = (float*)ws;                 ws += (size_t)NUSER * HDIM * 4;   // 51.2 MB
  float* cnt_g = (float*)ws;                 ws += (size_t)NGAME * 4;
  float* cnt_u = (float*)ws;                 ws += (size_t)NUSER * 4;

  float* out_user = (float*)d_out;                     // [NUSER][H]
  float* out_game = (float*)d_out + (size_t)NUSER * HDIM;  // [NGAME][H]

  // zero accumulators (ws is poisoned / stale between calls)
  hipMemsetAsync(sum_g, 0, (size_t)NGAME * HDIM * 4, stream);
  hipMemsetAsync(sum_u, 0, (size_t)NUSER * HDIM * 4, stream);
  hipMemsetAsync(cnt_g, 0, (size_t)NGAME * 4, stream);
  hipMemsetAsync(cnt_u, 0, (size_t)NUSER * 4, stream);

  // input projections + relu
  {
    int n = NUSER * HDIM;
    proj_kernel<64><<<(n + 255) / 256, 256, 0, stream>>>(x_user, W_user, b_user, hu, NUSER);
  }
  {
    int n = NGAME * HDIM;
    proj_kernel<128><<<(n + 255) / 256, 256, 0, stream>>>(x_game, W_game, b_game, hg, NGAME);
  }

  // edge scatter (mean numerator + counts)
  {
    long long t = (long long)E * 32;
    scatter_kernel<<<(int)((t + 255) / 256), 256, 0, stream>>>(hu, src_ug, dst_ug, sum_g, cnt_g, E);
    scatter_kernel<<<(int)((t + 255) / 256), 256, 0, stream>>>(hg, src_gu, dst_gu, sum_u, cnt_u, E);
  }

  // output projections
  {
    int n = NGAME * HDIM;
    out_kernel<<<(n + 255) / 256, 256, 0, stream>>>(sum_g, cnt_g, hg, Wl_ug, bl_ug, Wr_ug, out_game, NGAME);
  }
  {
    int n = NUSER * HDIM;
    out_kernel<<<(n + 255) / 256, 256, 0, stream>>>(sum_u, cnt_u, hu, Wl_gu, bl_gu, Wr_gu, out_user, NUSER);
  }
}

// Round 2
// 1718.150 us; speedup vs baseline: 3.8975x; 3.8975x over previous
//
#include <hip/hip_runtime.h>
#include <hip/hip_bf16.h>

#define NUSER 100000
#define NGAME 20000
#define HDIM  128

// ---------------------------------------------------------------------------
// proj: out[r][c] = relu(b[c] + sum_k x[r][k] * W[k][c]),  W row-major [K][H]
// ---------------------------------------------------------------------------
template <int K>
__global__ __launch_bounds__(256) void proj_kernel(
    const float* __restrict__ x, const float* __restrict__ W,
    const float* __restrict__ b, float* __restrict__ out, int n_rows) {
  int i = blockIdx.x * blockDim.x + threadIdx.x;
  if (i >= n_rows * HDIM) return;
  int r = i >> 7;
  int c = i & (HDIM - 1);
  const float* xr = x + (size_t)r * K;
  float acc = b[c];
#pragma unroll
  for (int k = 0; k < K; ++k) acc = fmaf(xr[k], W[k * HDIM + c], acc);
  out[i] = fmaxf(acc, 0.0f);
}

// ---------------------------------------------------------------------------
// hist: cnt[dst[e]] += 1
// ---------------------------------------------------------------------------
__global__ __launch_bounds__(256) void hist_kernel(
    const int* __restrict__ dst, int* __restrict__ cnt, int nE) {
  int e = blockIdx.x * blockDim.x + threadIdx.x;
  if (e < nE) atomicAdd(&cnt[dst[e]], 1);
}

// ---------------------------------------------------------------------------
// scan: exclusive prefix sum of cnt[0..n) -> off[0..n], single 1024-thr block
// ---------------------------------------------------------------------------
__global__ __launch_bounds__(1024) void scan_kernel(
    const int* __restrict__ cnt, int* __restrict__ off, int n) {
  __shared__ int wsum[16];
  __shared__ int carry_s;
  int lane = threadIdx.x & 63, wid = threadIdx.x >> 6;
  if (threadIdx.x == 0) carry_s = 0;
  __syncthreads();
  for (int base = 0; base < n; base += 1024) {
    int i = base + threadIdx.x;
    int v = (i < n) ? cnt[i] : 0;
    int x = v;
#pragma unroll
    for (int d = 1; d < 64; d <<= 1) {
      int t = __shfl_up(x, (unsigned)d, 64);
      if (lane >= d) x += t;
    }
    if (lane == 63) wsum[wid] = x;
    __syncthreads();
    if (wid == 0 && lane < 16) {
      int w = wsum[lane];
#pragma unroll
      for (int d = 1; d < 16; d <<= 1) {
        int t = __shfl_up(w, (unsigned)d, 64);
        if (lane >= d) w += t;
      }
      wsum[lane] = w;  // inclusive over wave sums
    }
    __syncthreads();
    int wavepre = (wid == 0) ? 0 : wsum[wid - 1];
    int carry = carry_s;
    if (i < n) off[i] = carry + wavepre + x - v;  // exclusive
    __syncthreads();
    if (threadIdx.x == 1023) carry_s = carry + wsum[15];
    __syncthreads();
  }
  if (threadIdx.x == 0) off[n] = carry_s;
}

// ---------------------------------------------------------------------------
// fill: esrc[off[dst[e]] + slot] = src[e]
// ---------------------------------------------------------------------------
__global__ __launch_bounds__(256) void fill_kernel(
    const int* __restrict__ src, const int* __restrict__ dst,
    const int* __restrict__ off, int* __restrict__ run,
    int* __restrict__ esrc, int nE) {
  int e = blockIdx.x * blockDim.x + threadIdx.x;
  if (e >= nE) return;
  int d = dst[e];
  int pos = off[d] + atomicAdd(&run[d], 1);
  esrc[pos] = src[e];
}

// ---------------------------------------------------------------------------
// gather: one wave per dst row; mean of gathered source rows -> m[row][:]
// ---------------------------------------------------------------------------
__global__ __launch_bounds__(256) void gather_kernel(
    const float* __restrict__ feat, const int* __restrict__ esrc,
    const int* __restrict__ off, float* __restrict__ m, int n_dst) {
  int w = (blockIdx.x * blockDim.x + threadIdx.x) >> 6;  // one wave per row
  int lane = threadIdx.x & 63;
  if (w >= n_dst) return;
  int beg = off[w], end = off[w + 1];
  const float2* f2 = (const float2*)feat;
  float ax = 0.0f, ay = 0.0f;
  int k = beg;
  for (; k + 4 <= end; k += 4) {
    int s0 = esrc[k], s1 = esrc[k + 1], s2 = esrc[k + 2], s3 = esrc[k + 3];
    float2 a = f2[(size_t)s0 * 64 + lane];
    float2 b = f2[(size_t)s1 * 64 + lane];
    float2 c = f2[(size_t)s2 * 64 + lane];
    float2 d = f2[(size_t)s3 * 64 + lane];
    ax += a.x + b.x + c.x + d.x;
    ay += a.y + b.y + c.y + d.y;
  }
  for (; k < end; ++k) {
    int s = esrc[k];
    float2 a = f2[(size_t)s * 64 + lane];
    ax += a.x;
    ay += a.y;
  }
  float inv = 1.0f / fmaxf((float)(end - beg), 1.0f);
  ((float2*)m)[(size_t)w * 64 + lane] = make_float2(ax * inv, ay * inv);
}

// ---------------------------------------------------------------------------
// out: out[r][c] = bl[c] + m[r][:] . Wl[:][c] + h[r][:] . Wr[:][c]
// ---------------------------------------------------------------------------
__global__ __launch_bounds__(256) void out_kernel(
    const float* __restrict__ m, const float* __restrict__ h,
    const float* __restrict__ Wl, const float* __restrict__ bl,
    const float* __restrict__ Wr, float* __restrict__ out, int n_rows) {
  int i = blockIdx.x * blockDim.x + threadIdx.x;
  if (i >= n_rows * HDIM) return;
  int r = i >> 7;
  int c = i & (HDIM - 1);
  const float* mr = m + (size_t)r * HDIM;
  const float* hr = h + (size_t)r * HDIM;
  float acc_m = 0.0f;
  float acc_h = 0.0f;
#pragma unroll
  for (int k = 0; k < HDIM; ++k) {
    acc_m = fmaf(mr[k], Wl[k * HDIM + c], acc_m);
    acc_h = fmaf(hr[k], Wr[k * HDIM + c], acc_h);
  }
  out[i] = bl[c] + acc_m + acc_h;
}

extern "C" void kernel_launch(void* const* d_in, const int* in_sizes, int n_in,
                              void* d_out, int out_size, void* d_ws, size_t ws_size,
                              hipStream_t stream) {
  const float* x_user = (const float*)d_in[0];
  const float* x_game = (const float*)d_in[1];
  const float* W_user = (const float*)d_in[2];
  const float* b_user = (const float*)d_in[3];
  const float* W_game = (const float*)d_in[4];
  const float* b_game = (const float*)d_in[5];
  const float* Wl_ug  = (const float*)d_in[6];
  const float* bl_ug  = (const float*)d_in[7];
  const float* Wr_ug  = (const float*)d_in[8];
  const float* Wl_gu  = (const float*)d_in[9];
  const float* bl_gu  = (const float*)d_in[10];
  const float* Wr_gu  = (const float*)d_in[11];
  const int*   src_ug = (const int*)d_in[12];
  const int*   dst_ug = (const int*)d_in[13];
  const int*   src_gu = (const int*)d_in[14];
  const int*   dst_gu = (const int*)d_in[15];
  const int E = in_sizes[12];

  // workspace carve. m_g aliases m_u (m_g dead before m_u is written).
  char* ws = (char*)d_ws;
  float* hu   = (float*)ws;  ws += (size_t)NUSER * HDIM * 4;   // 51.2 MB
  float* hg   = (float*)ws;  ws += (size_t)NGAME * HDIM * 4;   // 10.24 MB
  float* m_u  = (float*)ws;  ws += (size_t)NUSER * HDIM * 4;   // 51.2 MB
  float* m_g  = m_u;                                           // alias
  int*   esrc = (int*)ws;    ws += (size_t)E * 4;              // 6.4 MB
  int*   cnt  = (int*)ws;    ws += (size_t)(NUSER) * 4;
  int*   off  = (int*)ws;    ws += (size_t)(NUSER + 1) * 4;
  int*   run  = (int*)ws;    ws += (size_t)(NUSER) * 4;

  float* out_user = (float*)d_out;                         // [NUSER][H]
  float* out_game = (float*)d_out + (size_t)NUSER * HDIM;  // [NGAME][H]

  const int eb = (E + 255) / 256;

  // input projections + relu
  proj_kernel<64><<<(NUSER * HDIM + 255) / 256, 256, 0, stream>>>(x_user, W_user, b_user, hu, NUSER);
  proj_kernel<128><<<(NGAME * HDIM + 255) / 256, 256, 0, stream>>>(x_game, W_game, b_game, hg, NGAME);

  // ---- relation user->game (dst = games) ----
  hipMemsetAsync(cnt, 0, (size_t)NGAME * 4, stream);
  hipMemsetAsync(run, 0, (size_t)NGAME * 4, stream);
  hist_kernel<<<eb, 256, 0, stream>>>(dst_ug, cnt, E);
  scan_kernel<<<1, 1024, 0, stream>>>(cnt, off, NGAME);
  fill_kernel<<<eb, 256, 0, stream>>>(src_ug, dst_ug, off, run, esrc, E);
  gather_kernel<<<(NGAME * 64 + 255) / 256, 256, 0, stream>>>(hu, esrc, off, m_g, NGAME);
  out_kernel<<<(NGAME * HDIM + 255) / 256, 256, 0, stream>>>(m_g, hg, Wl_ug, bl_ug, Wr_ug, out_game, NGAME);

  // ---- relation game->user (dst = users) ----
  hipMemsetAsync(cnt, 0, (size_t)NUSER * 4, stream);
  hipMemsetAsync(run, 0, (size_t)NUSER * 4, stream);
  hist_kernel<<<eb, 256, 0, stream>>>(dst_gu, cnt, E);
  scan_kernel<<<1, 1024, 0, stream>>>(cnt, off, NUSER);
  fill_kernel<<<eb, 256, 0, stream>>>(src_gu, dst_gu, off, run, esrc, E);
  gather_kernel<<<(NUSER * 64 + 255) / 256, 256, 0, stream>>>(hg, esrc, off, m_u, NUSER);
  out_kernel<<<(NUSER * HDIM + 255) / 256, 256, 0, stream>>>(m_u, hu, Wl_gu, bl_gu, Wr_gu, out_user, NUSER);
}

// Round 3
// 867.851 us; speedup vs baseline: 7.7162x; 1.9798x over previous
//
#include <hip/hip_runtime.h>
#include <hip/hip_bf16.h>

#define NUSER 100000
#define NGAME 20000
#define HDIM  128

// ---------------------------------------------------------------------------
// proj_tiled: out[r][c] = relu(b[c] + sum_k x[r][k] * W[k][c])
// 16 rows per block staged in LDS; 256 threads = col (0..127) x rowgroup (0..1);
// each thread accumulates 8 rows -> each W element reused 8x from registers.
// ---------------------------------------------------------------------------
template <int K>
__global__ __launch_bounds__(256) void proj_tiled_kernel(
    const float* __restrict__ x, const float* __restrict__ W,
    const float* __restrict__ b, float* __restrict__ out) {
  __shared__ float xs[16][K];
  int r0 = blockIdx.x * 16;
  // stage 16 rows of x (16*K floats) via float4
  {
    const float4* src = (const float4*)(x + (size_t)r0 * K);
    float4* dst = (float4*)&xs[0][0];
    const int n4 = 16 * K / 4;
    for (int i = threadIdx.x; i < n4; i += 256) dst[i] = src[i];
  }
  __syncthreads();
  int c = threadIdx.x & 127;
  int rg = (threadIdx.x >> 7) * 8;  // 0 or 8
  float bias = b[c];
  float acc[8];
#pragma unroll
  for (int r = 0; r < 8; ++r) acc[r] = bias;
#pragma unroll 2
  for (int k = 0; k < K; k += 4) {
    float w0 = W[(k + 0) * HDIM + c];
    float w1 = W[(k + 1) * HDIM + c];
    float w2 = W[(k + 2) * HDIM + c];
    float w3 = W[(k + 3) * HDIM + c];
#pragma unroll
    for (int r = 0; r < 8; ++r) {
      float4 xv = *(const float4*)&xs[rg + r][k];
      acc[r] = fmaf(xv.x, w0, acc[r]);
      acc[r] = fmaf(xv.y, w1, acc[r]);
      acc[r] = fmaf(xv.z, w2, acc[r]);
      acc[r] = fmaf(xv.w, w3, acc[r]);
    }
  }
#pragma unroll
  for (int r = 0; r < 8; ++r)
    out[(size_t)(r0 + rg + r) * HDIM + c] = fmaxf(acc[r], 0.0f);
}

// ---------------------------------------------------------------------------
// out_tiled: out[r][c] = bl[c] + m[r][:].Wl[:][c] + h[r][:].Wr[:][c]
// same 16-row register-blocked scheme, two K=128 passes (m/Wl then h/Wr).
// ---------------------------------------------------------------------------
__global__ __launch_bounds__(256) void out_tiled_kernel(
    const float* __restrict__ m, const float* __restrict__ h,
    const float* __restrict__ Wl, const float* __restrict__ bl,
    const float* __restrict__ Wr, float* __restrict__ out) {
  __shared__ float ms[16][HDIM];
  __shared__ float hs[16][HDIM];
  int r0 = blockIdx.x * 16;
  {
    const float4* srcm = (const float4*)(m + (size_t)r0 * HDIM);
    const float4* srch = (const float4*)(h + (size_t)r0 * HDIM);
    float4* dstm = (float4*)&ms[0][0];
    float4* dsth = (float4*)&hs[0][0];
    for (int i = threadIdx.x; i < 16 * HDIM / 4; i += 256) {
      dstm[i] = srcm[i];
      dsth[i] = srch[i];
    }
  }
  __syncthreads();
  int c = threadIdx.x & 127;
  int rg = (threadIdx.x >> 7) * 8;
  float bias = bl[c];
  float acc[8];
#pragma unroll
  for (int r = 0; r < 8; ++r) acc[r] = bias;
#pragma unroll 2
  for (int k = 0; k < HDIM; k += 4) {
    float wl0 = Wl[(k + 0) * HDIM + c];
    float wl1 = Wl[(k + 1) * HDIM + c];
    float wl2 = Wl[(k + 2) * HDIM + c];
    float wl3 = Wl[(k + 3) * HDIM + c];
    float wr0 = Wr[(k + 0) * HDIM + c];
    float wr1 = Wr[(k + 1) * HDIM + c];
    float wr2 = Wr[(k + 2) * HDIM + c];
    float wr3 = Wr[(k + 3) * HDIM + c];
#pragma unroll
    for (int r = 0; r < 8; ++r) {
      float4 mv = *(const float4*)&ms[rg + r][k];
      float4 hv = *(const float4*)&hs[rg + r][k];
      acc[r] = fmaf(mv.x, wl0, acc[r]);
      acc[r] = fmaf(mv.y, wl1, acc[r]);
      acc[r] = fmaf(mv.z, wl2, acc[r]);
      acc[r] = fmaf(mv.w, wl3, acc[r]);
      acc[r] = fmaf(hv.x, wr0, acc[r]);
      acc[r] = fmaf(hv.y, wr1, acc[r]);
      acc[r] = fmaf(hv.z, wr2, acc[r]);
      acc[r] = fmaf(hv.w, wr3, acc[r]);
    }
  }
#pragma unroll
  for (int r = 0; r < 8; ++r)
    out[(size_t)(r0 + rg + r) * HDIM + c] = acc[r];
}

// ---------------------------------------------------------------------------
// hist: cnt[dst[e]] += 1
// ---------------------------------------------------------------------------
__global__ __launch_bounds__(256) void hist_kernel(
    const int* __restrict__ dst, int* __restrict__ cnt, int nE) {
  int e = blockIdx.x * blockDim.x + threadIdx.x;
  if (e < nE) atomicAdd(&cnt[dst[e]], 1);
}

// ---------------------------------------------------------------------------
// scan: exclusive prefix sum of cnt[0..n) -> off[0..n], single 1024-thr block
// ---------------------------------------------------------------------------
__global__ __launch_bounds__(1024) void scan_kernel(
    const int* __restrict__ cnt, int* __restrict__ off, int n) {
  __shared__ int wsum[16];
  __shared__ int carry_s;
  int lane = threadIdx.x & 63, wid = threadIdx.x >> 6;
  if (threadIdx.x == 0) carry_s = 0;
  __syncthreads();
  for (int base = 0; base < n; base += 1024) {
    int i = base + threadIdx.x;
    int v = (i < n) ? cnt[i] : 0;
    int x = v;
#pragma unroll
    for (int d = 1; d < 64; d <<= 1) {
      int t = __shfl_up(x, (unsigned)d, 64);
      if (lane >= d) x += t;
    }
    if (lane == 63) wsum[wid] = x;
    __syncthreads();
    if (wid == 0 && lane < 16) {
      int w = wsum[lane];
#pragma unroll
      for (int d = 1; d < 16; d <<= 1) {
        int t = __shfl_up(w, (unsigned)d, 64);
        if (lane >= d) w += t;
      }
      wsum[lane] = w;  // inclusive over wave sums
    }
    __syncthreads();
    int wavepre = (wid == 0) ? 0 : wsum[wid - 1];
    int carry = carry_s;
    if (i < n) off[i] = carry + wavepre + x - v;  // exclusive
    __syncthreads();
    if (threadIdx.x == 1023) carry_s = carry + wsum[15];
    __syncthreads();
  }
  if (threadIdx.x == 0) off[n] = carry_s;
}

// ---------------------------------------------------------------------------
// fill: esrc[off[dst[e]] + slot] = src[e]
// ---------------------------------------------------------------------------
__global__ __launch_bounds__(256) void fill_kernel(
    const int* __restrict__ src, const int* __restrict__ dst,
    const int* __restrict__ off, int* __restrict__ run,
    int* __restrict__ esrc, int nE) {
  int e = blockIdx.x * blockDim.x + threadIdx.x;
  if (e >= nE) return;
  int d = dst[e];
  int pos = off[d] + atomicAdd(&run[d], 1);
  esrc[pos] = src[e];
}

// ---------------------------------------------------------------------------
// gather: one wave per dst row; mean of gathered source rows -> m[row][:]
// ---------------------------------------------------------------------------
__global__ __launch_bounds__(256) void gather_kernel(
    const float* __restrict__ feat, const int* __restrict__ esrc,
    const int* __restrict__ off, float* __restrict__ m, int n_dst) {
  int w = (blockIdx.x * blockDim.x + threadIdx.x) >> 6;  // one wave per row
  int lane = threadIdx.x & 63;
  if (w >= n_dst) return;
  int beg = off[w], end = off[w + 1];
  const float2* f2 = (const float2*)feat;
  float ax = 0.0f, ay = 0.0f;
  int k = beg;
  for (; k + 4 <= end; k += 4) {
    int s0 = esrc[k], s1 = esrc[k + 1], s2 = esrc[k + 2], s3 = esrc[k + 3];
    float2 a = f2[(size_t)s0 * 64 + lane];
    float2 b = f2[(size_t)s1 * 64 + lane];
    float2 c = f2[(size_t)s2 * 64 + lane];
    float2 d = f2[(size_t)s3 * 64 + lane];
    ax += a.x + b.x + c.x + d.x;
    ay += a.y + b.y + c.y + d.y;
  }
  for (; k < end; ++k) {
    int s = esrc[k];
    float2 a = f2[(size_t)s * 64 + lane];
    ax += a.x;
    ay += a.y;
  }
  float inv = 1.0f / fmaxf((float)(end - beg), 1.0f);
  ((float2*)m)[(size_t)w * 64 + lane] = make_float2(ax * inv, ay * inv);
}

extern "C" void kernel_launch(void* const* d_in, const int* in_sizes, int n_in,
                              void* d_out, int out_size, void* d_ws, size_t ws_size,
                              hipStream_t stream) {
  const float* x_user = (const float*)d_in[0];
  const float* x_game = (const float*)d_in[1];
  const float* W_user = (const float*)d_in[2];
  const float* b_user = (const float*)d_in[3];
  const float* W_game = (const float*)d_in[4];
  const float* b_game = (const float*)d_in[5];
  const float* Wl_ug  = (const float*)d_in[6];
  const float* bl_ug  = (const float*)d_in[7];
  const float* Wr_ug  = (const float*)d_in[8];
  const float* Wl_gu  = (const float*)d_in[9];
  const float* bl_gu  = (const float*)d_in[10];
  const float* Wr_gu  = (const float*)d_in[11];
  const int*   src_ug = (const int*)d_in[12];
  const int*   dst_ug = (const int*)d_in[13];
  const int*   src_gu = (const int*)d_in[14];
  const int*   dst_gu = (const int*)d_in[15];
  const int E = in_sizes[12];

  // workspace carve. m_g aliases m_u (m_g dead before m_u is written).
  char* ws = (char*)d_ws;
  float* hu   = (float*)ws;  ws += (size_t)NUSER * HDIM * 4;   // 51.2 MB
  float* hg   = (float*)ws;  ws += (size_t)NGAME * HDIM * 4;   // 10.24 MB
  float* m_u  = (float*)ws;  ws += (size_t)NUSER * HDIM * 4;   // 51.2 MB
  float* m_g  = m_u;                                           // alias
  int*   esrc = (int*)ws;    ws += (size_t)E * 4;              // 6.4 MB
  int*   cnt  = (int*)ws;    ws += (size_t)(NUSER) * 4;
  int*   off  = (int*)ws;    ws += (size_t)(NUSER + 1) * 4;
  int*   run  = (int*)ws;    ws += (size_t)(NUSER) * 4;

  float* out_user = (float*)d_out;                         // [NUSER][H]
  float* out_game = (float*)d_out + (size_t)NUSER * HDIM;  // [NGAME][H]

  const int eb = (E + 255) / 256;

  // input projections + relu (16 rows/block; 100000 and 20000 are /16)
  proj_tiled_kernel<64><<<NUSER / 16, 256, 0, stream>>>(x_user, W_user, b_user, hu);
  proj_tiled_kernel<128><<<NGAME / 16, 256, 0, stream>>>(x_game, W_game, b_game, hg);

  // ---- relation user->game (dst = games) ----
  hipMemsetAsync(cnt, 0, (size_t)NGAME * 4, stream);
  hipMemsetAsync(run, 0, (size_t)NGAME * 4, stream);
  hist_kernel<<<eb, 256, 0, stream>>>(dst_ug, cnt, E);
  scan_kernel<<<1, 1024, 0, stream>>>(cnt, off, NGAME);
  fill_kernel<<<eb, 256, 0, stream>>>(src_ug, dst_ug, off, run, esrc, E);
  gather_kernel<<<(NGAME * 64 + 255) / 256, 256, 0, stream>>>(hu, esrc, off, m_g, NGAME);
  out_tiled_kernel<<<NGAME / 16, 256, 0, stream>>>(m_g, hg, Wl_ug, bl_ug, Wr_ug, out_game);

  // ---- relation game->user (dst = users) ----
  hipMemsetAsync(cnt, 0, (size_t)NUSER * 4, stream);
  hipMemsetAsync(run, 0, (size_t)NUSER * 4, stream);
  hist_kernel<<<eb, 256, 0, stream>>>(dst_gu, cnt, E);
  scan_kernel<<<1, 1024, 0, stream>>>(cnt, off, NUSER);
  fill_kernel<<<eb, 256, 0, stream>>>(src_gu, dst_gu, off, run, esrc, E);
  gather_kernel<<<(NUSER * 64 + 255) / 256, 256, 0, stream>>>(hg, esrc, off, m_u, NUSER);
  out_tiled_kernel<<<NUSER / 16, 256, 0, stream>>>(m_u, hu, Wl_gu, bl_gu, Wr_gu, out_user);
}

// Round 4
// 549.438 us; speedup vs baseline: 12.1879x; 1.5795x over previous
//
#include <hip/hip_runtime.h>
#include <hip/hip_bf16.h>

#define NUSER 100000
#define NGAME 20000
#define HDIM  128

typedef short bf16x8 __attribute__((ext_vector_type(8)));
typedef float f32x4  __attribute__((ext_vector_type(4)));

__device__ __forceinline__ unsigned short f2b(float f) {
  union { float f; unsigned u; } a;
  a.f = f;
  unsigned r = a.u + 0x7fff + ((a.u >> 16) & 1);  // RNE
  return (unsigned short)(r >> 16);
}
__device__ __forceinline__ float b2f_lo(unsigned u) {
  union { unsigned u; float f; } a; a.u = u << 16; return a.f;
}
__device__ __forceinline__ float b2f_hi(unsigned u) {
  union { unsigned u; float f; } a; a.u = u & 0xffff0000u; return a.f;
}

// ---------------------------------------------------------------------------
// repack: W[K][128] f32 -> fragment-ordered bf16 for mfma_f32_16x16x32_bf16
// layout: frag[(kt*8+nt)*64 + lane][8], elem b = W[kt*32+(lane>>4)*8+b][nt*16+(lane&15)]
// ---------------------------------------------------------------------------
__global__ __launch_bounds__(256) void repack_kernel(
    const float* __restrict__ W0, const float* __restrict__ W1,
    const float* __restrict__ W2, const float* __restrict__ W3,
    const float* __restrict__ W4, const float* __restrict__ W5,
    unsigned short* __restrict__ P0, unsigned short* __restrict__ P1,
    unsigned short* __restrict__ P2, unsigned short* __restrict__ P3,
    unsigned short* __restrict__ P4, unsigned short* __restrict__ P5) {
  const float* W; unsigned short* P; int K;
  switch (blockIdx.y) {
    case 0: W = W0; P = P0; K = 64;  break;
    case 1: W = W1; P = P1; K = 128; break;
    case 2: W = W2; P = P2; K = 128; break;
    case 3: W = W3; P = P3; K = 128; break;
    case 4: W = W4; P = P4; K = 128; break;
    default: W = W5; P = P5; K = 128; break;
  }
  int t = blockIdx.x * 256 + threadIdx.x;
  int KT = K / 32;
  if (t >= KT * 8 * 64) return;
  int lane = t & 63;
  int nt = (t >> 6) & 7;
  int kt = t >> 9;
  int col = nt * 16 + (lane & 15);
  int krow = kt * 32 + (lane >> 4) * 8;
  unsigned short vals[8];
#pragma unroll
  for (int b = 0; b < 8; ++b) vals[b] = f2b(W[(size_t)(krow + b) * HDIM + col]);
  *reinterpret_cast<bf16x8*>(P + (size_t)t * 8) = *reinterpret_cast<bf16x8*>(vals);
}

// ---------------------------------------------------------------------------
// proj_mfma: h = relu(x @ W + b), x f32 [M][K], W prepacked bf16, h bf16 [M][128]
// block = 4 waves, 64 rows/block; wave = 16 rows x 128 cols, K-loop of 32
// ---------------------------------------------------------------------------
template <int K>
__global__ __launch_bounds__(256) void proj_mfma_kernel(
    const float* __restrict__ x, const unsigned short* __restrict__ Wp,
    const float* __restrict__ b, unsigned short* __restrict__ h, int M) {
  int l = threadIdx.x & 63;
  int wid = threadIdx.x >> 6;
  int r0 = blockIdx.x * 64 + wid * 16;
  int arow = r0 + (l & 15);
  if (arow >= M) arow = M - 1;
  const int KT = K / 32;
  f32x4 acc[8];
#pragma unroll
  for (int nt = 0; nt < 8; ++nt) acc[nt] = (f32x4){0.f, 0.f, 0.f, 0.f};
  const float* xr = x + (size_t)arow * K + (l >> 4) * 8;
  const bf16x8* Wf = (const bf16x8*)Wp;
#pragma unroll
  for (int kt = 0; kt < KT; ++kt) {
    float4 a0 = *(const float4*)(xr + kt * 32);
    float4 a1 = *(const float4*)(xr + kt * 32 + 4);
    bf16x8 af;
    af[0] = (short)f2b(a0.x); af[1] = (short)f2b(a0.y);
    af[2] = (short)f2b(a0.z); af[3] = (short)f2b(a0.w);
    af[4] = (short)f2b(a1.x); af[5] = (short)f2b(a1.y);
    af[6] = (short)f2b(a1.z); af[7] = (short)f2b(a1.w);
#pragma unroll
    for (int nt = 0; nt < 8; ++nt) {
      bf16x8 bf = Wf[(kt * 8 + nt) * 64 + l];
      acc[nt] = __builtin_amdgcn_mfma_f32_16x16x32_bf16(af, bf, acc[nt], 0, 0, 0);
    }
  }
  int rbase = r0 + ((l >> 4) << 2);
#pragma unroll
  for (int nt = 0; nt < 8; ++nt) {
    int col = nt * 16 + (l & 15);
    float bias = b[col];
#pragma unroll
    for (int r = 0; r < 4; ++r) {
      int row = rbase + r;
      if (row < M) h[(size_t)row * HDIM + col] = f2b(fmaxf(acc[nt][r] + bias, 0.f));
    }
  }
}

// ---------------------------------------------------------------------------
// out_mfma: out = m @ Wl + h @ Wr + bl   (m,h bf16 [M][128]; out f32)
// ---------------------------------------------------------------------------
__global__ __launch_bounds__(256) void out_mfma_kernel(
    const unsigned short* __restrict__ m, const unsigned short* __restrict__ h,
    const unsigned short* __restrict__ WlP, const float* __restrict__ bl,
    const unsigned short* __restrict__ WrP, float* __restrict__ out, int M) {
  int l = threadIdx.x & 63;
  int wid = threadIdx.x >> 6;
  int r0 = blockIdx.x * 64 + wid * 16;
  int arow = r0 + (l & 15);
  if (arow >= M) arow = M - 1;
  f32x4 acc[8];
#pragma unroll
  for (int nt = 0; nt < 8; ++nt) acc[nt] = (f32x4){0.f, 0.f, 0.f, 0.f};
  const unsigned short* mr = m + (size_t)arow * HDIM + (l >> 4) * 8;
  const unsigned short* hr = h + (size_t)arow * HDIM + (l >> 4) * 8;
  const bf16x8* Wlf = (const bf16x8*)WlP;
  const bf16x8* Wrf = (const bf16x8*)WrP;
#pragma unroll
  for (int kt = 0; kt < 4; ++kt) {
    bf16x8 am = *(const bf16x8*)(mr + kt * 32);
    bf16x8 ah = *(const bf16x8*)(hr + kt * 32);
#pragma unroll
    for (int nt = 0; nt < 8; ++nt) {
      bf16x8 bl_f = Wlf[(kt * 8 + nt) * 64 + l];
      bf16x8 br_f = Wrf[(kt * 8 + nt) * 64 + l];
      acc[nt] = __builtin_amdgcn_mfma_f32_16x16x32_bf16(am, bl_f, acc[nt], 0, 0, 0);
      acc[nt] = __builtin_amdgcn_mfma_f32_16x16x32_bf16(ah, br_f, acc[nt], 0, 0, 0);
    }
  }
  int rbase = r0 + ((l >> 4) << 2);
#pragma unroll
  for (int nt = 0; nt < 8; ++nt) {
    int col = nt * 16 + (l & 15);
    float bias = bl[col];
#pragma unroll
    for (int r = 0; r < 4; ++r) {
      int row = rbase + r;
      if (row < M) out[(size_t)row * HDIM + col] = acc[nt][r] + bias;
    }
  }
}

// ---------------------------------------------------------------------------
// hist: cnt[dst[e]] += 1
// ---------------------------------------------------------------------------
__global__ __launch_bounds__(256) void hist_kernel(
    const int* __restrict__ dst, int* __restrict__ cnt, int nE) {
  int e = blockIdx.x * blockDim.x + threadIdx.x;
  if (e < nE) atomicAdd(&cnt[dst[e]], 1);
}

// ---------------------------------------------------------------------------
// 3-phase exclusive scan of cnt[0..n) -> off[0..n]
// ---------------------------------------------------------------------------
__global__ __launch_bounds__(1024) void scan1_kernel(
    const int* __restrict__ cnt, int* __restrict__ off,
    int* __restrict__ bsum, int n) {
  __shared__ int wsum[16];
  int i = blockIdx.x * 1024 + threadIdx.x;
  int lane = threadIdx.x & 63, wid = threadIdx.x >> 6;
  int v = (i < n) ? cnt[i] : 0;
  int x = v;
#pragma unroll
  for (int d = 1; d < 64; d <<= 1) {
    int t = __shfl_up(x, (unsigned)d, 64);
    if (lane >= d) x += t;
  }
  if (lane == 63) wsum[wid] = x;
  __syncthreads();
  if (wid == 0 && lane < 16) {
    int w = wsum[lane];
#pragma unroll
    for (int d = 1; d < 16; d <<= 1) {
      int t = __shfl_up(w, (unsigned)d, 64);
      if (lane >= d) w += t;
    }
    wsum[lane] = w;
  }
  __syncthreads();
  int wavepre = (wid == 0) ? 0 : wsum[wid - 1];
  if (i < n) off[i] = wavepre + x - v;
  if (threadIdx.x == 1023) bsum[blockIdx.x] = wavepre + x;
}

__global__ __launch_bounds__(128) void scan2_kernel(
    int* __restrict__ bsum, int* __restrict__ off, int nb, int n) {
  __shared__ int ws[2];
  int lane = threadIdx.x & 63, wid = threadIdx.x >> 6;
  int v = (threadIdx.x < nb) ? bsum[threadIdx.x] : 0;
  int x = v;
#pragma unroll
  for (int d = 1; d < 64; d <<= 1) {
    int t = __shfl_up(x, (unsigned)d, 64);
    if (lane >= d) x += t;
  }
  if (lane == 63) ws[wid] = x;
  __syncthreads();
  int pre = (wid == 0) ? 0 : ws[0];
  if (threadIdx.x < nb) bsum[threadIdx.x] = pre + x - v;  // exclusive
  if (threadIdx.x == 127) off[n] = pre + x;               // grand total
}

__global__ __launch_bounds__(256) void scan3_kernel(
    int* __restrict__ off, const int* __restrict__ bsum, int n) {
  int i = blockIdx.x * 256 + threadIdx.x;
  if (i < n) off[i] += bsum[i >> 10];
}

// ---------------------------------------------------------------------------
// fill: esrc[off[dst[e]] + slot] = src[e]
// ---------------------------------------------------------------------------
__global__ __launch_bounds__(256) void fill_kernel(
    const int* __restrict__ src, const int* __restrict__ dst,
    const int* __restrict__ off, int* __restrict__ run,
    int* __restrict__ esrc, int nE) {
  int e = blockIdx.x * blockDim.x + threadIdx.x;
  if (e >= nE) return;
  int d = dst[e];
  int pos = off[d] + atomicAdd(&run[d], 1);
  esrc[pos] = src[e];
}

// ---------------------------------------------------------------------------
// gather: one wave per dst row; mean of bf16 source rows -> bf16 m[row][:]
// lane covers cols 2*lane, 2*lane+1 (uint = bf16x2)
// ---------------------------------------------------------------------------
__global__ __launch_bounds__(256) void gather_kernel(
    const unsigned short* __restrict__ feat, const int* __restrict__ esrc,
    const int* __restrict__ off, unsigned short* __restrict__ m, int n_dst) {
  int w = (blockIdx.x * blockDim.x + threadIdx.x) >> 6;
  int lane = threadIdx.x & 63;
  if (w >= n_dst) return;
  int beg = off[w], end = off[w + 1];
  const unsigned* f = (const unsigned*)feat;  // row stride 64 uints
  float ax = 0.f, ay = 0.f;
  int k = beg;
  for (; k + 4 <= end; k += 4) {
    int s0 = esrc[k], s1 = esrc[k + 1], s2 = esrc[k + 2], s3 = esrc[k + 3];
    unsigned a = f[(size_t)s0 * 64 + lane];
    unsigned b = f[(size_t)s1 * 64 + lane];
    unsigned c = f[(size_t)s2 * 64 + lane];
    unsigned d = f[(size_t)s3 * 64 + lane];
    ax += b2f_lo(a) + b2f_lo(b) + b2f_lo(c) + b2f_lo(d);
    ay += b2f_hi(a) + b2f_hi(b) + b2f_hi(c) + b2f_hi(d);
  }
  for (; k < end; ++k) {
    unsigned a = f[(size_t)esrc[k] * 64 + lane];
    ax += b2f_lo(a);
    ay += b2f_hi(a);
  }
  float inv = 1.f / fmaxf((float)(end - beg), 1.f);
  unsigned o = (unsigned)f2b(ax * inv) | ((unsigned)f2b(ay * inv) << 16);
  ((unsigned*)m)[(size_t)w * 64 + lane] = o;
}

extern "C" void kernel_launch(void* const* d_in, const int* in_sizes, int n_in,
                              void* d_out, int out_size, void* d_ws, size_t ws_size,
                              hipStream_t stream) {
  const float* x_user = (const float*)d_in[0];
  const float* x_game = (const float*)d_in[1];
  const float* W_user = (const float*)d_in[2];
  const float* b_user = (const float*)d_in[3];
  const float* W_game = (const float*)d_in[4];
  const float* b_game = (const float*)d_in[5];
  const float* Wl_ug  = (const float*)d_in[6];
  const float* bl_ug  = (const float*)d_in[7];
  const float* Wr_ug  = (const float*)d_in[8];
  const float* Wl_gu  = (const float*)d_in[9];
  const float* bl_gu  = (const float*)d_in[10];
  const float* Wr_gu  = (const float*)d_in[11];
  const int*   src_ug = (const int*)d_in[12];
  const int*   dst_ug = (const int*)d_in[13];
  const int*   src_gu = (const int*)d_in[14];
  const int*   dst_gu = (const int*)d_in[15];
  const int E = in_sizes[12];

  // workspace carve (bf16 features). m_g aliases m_u.
  char* ws = (char*)d_ws;
  unsigned short* hu  = (unsigned short*)ws; ws += (size_t)NUSER * HDIM * 2;  // 25.6 MB
  unsigned short* hg  = (unsigned short*)ws; ws += (size_t)NGAME * HDIM * 2;  // 5.12 MB
  unsigned short* m_u = (unsigned short*)ws; ws += (size_t)NUSER * HDIM * 2;  // 25.6 MB
  unsigned short* m_g = m_u;
  int* esrc = (int*)ws;  ws += (size_t)E * 4;                                  // 6.4 MB
  int* cnt  = (int*)ws;  ws += (size_t)NUSER * 4;
  int* off  = (int*)ws;  ws += (size_t)(NUSER + 1) * 4;
  int* run  = (int*)ws;  ws += (size_t)NUSER * 4;
  int* bsum = (int*)ws;  ws += 256 * 4;
  unsigned short* P_wu  = (unsigned short*)ws; ws += (size_t)2 * 8 * 64 * 8 * 2;  // 16 KB
  unsigned short* P_wg  = (unsigned short*)ws; ws += (size_t)4 * 8 * 64 * 8 * 2;  // 32 KB
  unsigned short* P_lug = (unsigned short*)ws; ws += (size_t)4 * 8 * 64 * 8 * 2;
  unsigned short* P_rug = (unsigned short*)ws; ws += (size_t)4 * 8 * 64 * 8 * 2;
  unsigned short* P_lgu = (unsigned short*)ws; ws += (size_t)4 * 8 * 64 * 8 * 2;
  unsigned short* P_rgu = (unsigned short*)ws; ws += (size_t)4 * 8 * 64 * 8 * 2;

  float* out_user = (float*)d_out;
  float* out_game = (float*)d_out + (size_t)NUSER * HDIM;

  const int eb = (E + 255) / 256;

  // one-shot weight repack to MFMA fragment order (bf16)
  repack_kernel<<<dim3(8, 6), 256, 0, stream>>>(
      W_user, W_game, Wl_ug, Wr_ug, Wl_gu, Wr_gu,
      P_wu, P_wg, P_lug, P_rug, P_lgu, P_rgu);

  // input projections + relu (bf16 out)
  proj_mfma_kernel<64><<<(NUSER + 63) / 64, 256, 0, stream>>>(x_user, P_wu, b_user, hu, NUSER);
  proj_mfma_kernel<128><<<(NGAME + 63) / 64, 256, 0, stream>>>(x_game, P_wg, b_game, hg, NGAME);

  // ---- relation user->game (dst = games) ----
  {
    const int n = NGAME, nb = (n + 1023) / 1024;
    hipMemsetAsync(cnt, 0, (size_t)n * 4, stream);
    hipMemsetAsync(run, 0, (size_t)n * 4, stream);
    hist_kernel<<<eb, 256, 0, stream>>>(dst_ug, cnt, E);
    scan1_kernel<<<nb, 1024, 0, stream>>>(cnt, off, bsum, n);
    scan2_kernel<<<1, 128, 0, stream>>>(bsum, off, nb, n);
    scan3_kernel<<<(n + 255) / 256, 256, 0, stream>>>(off, bsum, n);
    fill_kernel<<<eb, 256, 0, stream>>>(src_ug, dst_ug, off, run, esrc, E);
    gather_kernel<<<(n * 64 + 255) / 256, 256, 0, stream>>>(hu, esrc, off, m_g, n);
    out_mfma_kernel<<<(n + 63) / 64, 256, 0, stream>>>(m_g, hg, P_lug, bl_ug, P_rug, out_game, n);
  }

  // ---- relation game->user (dst = users) ----
  {
    const int n = NUSER, nb = (n + 1023) / 1024;
    hipMemsetAsync(cnt, 0, (size_t)n * 4, stream);
    hipMemsetAsync(run, 0, (size_t)n * 4, stream);
    hist_kernel<<<eb, 256, 0, stream>>>(dst_gu, cnt, E);
    scan1_kernel<<<nb, 1024, 0, stream>>>(cnt, off, bsum, n);
    scan2_kernel<<<1, 128, 0, stream>>>(bsum, off, nb, n);
    scan3_kernel<<<(n + 255) / 256, 256, 0, stream>>>(off, bsum, n);
    fill_kernel<<<eb, 256, 0, stream>>>(src_gu, dst_gu, off, run, esrc, E);
    gather_kernel<<<(n * 64 + 255) / 256, 256, 0, stream>>>(hg, esrc, off, m_u, n);
    out_mfma_kernel<<<(n + 63) / 64, 256, 0, stream>>>(m_u, hu, P_lgu, bl_gu, P_rgu, out_user, n);
  }
}

// Round 5
// 527.447 us; speedup vs baseline: 12.6961x; 1.0417x over previous
//
#include <hip/hip_runtime.h>
#include <hip/hip_bf16.h>

#define NUSER 100000
#define NGAME 20000
#define HDIM  128
#define NPART 16
#define FCHUNK 4096

typedef short bf16x8 __attribute__((ext_vector_type(8)));
typedef float f32x4  __attribute__((ext_vector_type(4)));

__device__ __forceinline__ unsigned short f2b(float f) {
  union { float f; unsigned u; } a;
  a.f = f;
  unsigned r = a.u + 0x7fff + ((a.u >> 16) & 1);  // RNE
  return (unsigned short)(r >> 16);
}
__device__ __forceinline__ float b2f_lo(unsigned u) {
  union { unsigned u; float f; } a; a.u = u << 16; return a.f;
}
__device__ __forceinline__ float b2f_hi(unsigned u) {
  union { unsigned u; float f; } a; a.u = u & 0xffff0000u; return a.f;
}

// ---------------------------------------------------------------------------
// repack: W[K][128] f32 -> fragment-ordered bf16 for mfma_f32_16x16x32_bf16
// ---------------------------------------------------------------------------
__global__ __launch_bounds__(256) void repack_kernel(
    const float* __restrict__ W0, const float* __restrict__ W1,
    const float* __restrict__ W2, const float* __restrict__ W3,
    const float* __restrict__ W4, const float* __restrict__ W5,
    unsigned short* __restrict__ P0, unsigned short* __restrict__ P1,
    unsigned short* __restrict__ P2, unsigned short* __restrict__ P3,
    unsigned short* __restrict__ P4, unsigned short* __restrict__ P5) {
  const float* W; unsigned short* P; int K;
  switch (blockIdx.y) {
    case 0: W = W0; P = P0; K = 64;  break;
    case 1: W = W1; P = P1; K = 128; break;
    case 2: W = W2; P = P2; K = 128; break;
    case 3: W = W3; P = P3; K = 128; break;
    case 4: W = W4; P = P4; K = 128; break;
    default: W = W5; P = P5; K = 128; break;
  }
  int t = blockIdx.x * 256 + threadIdx.x;
  int KT = K / 32;
  if (t >= KT * 8 * 64) return;
  int lane = t & 63;
  int nt = (t >> 6) & 7;
  int kt = t >> 9;
  int col = nt * 16 + (lane & 15);
  int krow = kt * 32 + (lane >> 4) * 8;
  unsigned short vals[8];
#pragma unroll
  for (int b = 0; b < 8; ++b) vals[b] = f2b(W[(size_t)(krow + b) * HDIM + col]);
  *reinterpret_cast<bf16x8*>(P + (size_t)t * 8) = *reinterpret_cast<bf16x8*>(vals);
}

// ---------------------------------------------------------------------------
// proj_mfma: h = relu(x @ W + b), x f32 [M][K], W prepacked bf16, h bf16 [M][128]
// ---------------------------------------------------------------------------
template <int K>
__global__ __launch_bounds__(256) void proj_mfma_kernel(
    const float* __restrict__ x, const unsigned short* __restrict__ Wp,
    const float* __restrict__ b, unsigned short* __restrict__ h, int M) {
  int l = threadIdx.x & 63;
  int wid = threadIdx.x >> 6;
  int r0 = blockIdx.x * 64 + wid * 16;
  int arow = r0 + (l & 15);
  if (arow >= M) arow = M - 1;
  const int KT = K / 32;
  f32x4 acc[8];
#pragma unroll
  for (int nt = 0; nt < 8; ++nt) acc[nt] = (f32x4){0.f, 0.f, 0.f, 0.f};
  const float* xr = x + (size_t)arow * K + (l >> 4) * 8;
  const bf16x8* Wf = (const bf16x8*)Wp;
#pragma unroll
  for (int kt = 0; kt < KT; ++kt) {
    float4 a0 = *(const float4*)(xr + kt * 32);
    float4 a1 = *(const float4*)(xr + kt * 32 + 4);
    bf16x8 af;
    af[0] = (short)f2b(a0.x); af[1] = (short)f2b(a0.y);
    af[2] = (short)f2b(a0.z); af[3] = (short)f2b(a0.w);
    af[4] = (short)f2b(a1.x); af[5] = (short)f2b(a1.y);
    af[6] = (short)f2b(a1.z); af[7] = (short)f2b(a1.w);
#pragma unroll
    for (int nt = 0; nt < 8; ++nt) {
      bf16x8 bf = Wf[(kt * 8 + nt) * 64 + l];
      acc[nt] = __builtin_amdgcn_mfma_f32_16x16x32_bf16(af, bf, acc[nt], 0, 0, 0);
    }
  }
  int rbase = r0 + ((l >> 4) << 2);
#pragma unroll
  for (int nt = 0; nt < 8; ++nt) {
    int col = nt * 16 + (l & 15);
    float bias = b[col];
#pragma unroll
    for (int r = 0; r < 4; ++r) {
      int row = rbase + r;
      if (row < M) h[(size_t)row * HDIM + col] = f2b(fmaxf(acc[nt][r] + bias, 0.f));
    }
  }
}

// ---------------------------------------------------------------------------
// out_mfma: out = m @ Wl + h @ Wr + bl   (m,h bf16 [M][128]; out f32)
// ---------------------------------------------------------------------------
__global__ __launch_bounds__(256) void out_mfma_kernel(
    const unsigned short* __restrict__ m, const unsigned short* __restrict__ h,
    const unsigned short* __restrict__ WlP, const float* __restrict__ bl,
    const unsigned short* __restrict__ WrP, float* __restrict__ out, int M) {
  int l = threadIdx.x & 63;
  int wid = threadIdx.x >> 6;
  int r0 = blockIdx.x * 64 + wid * 16;
  int arow = r0 + (l & 15);
  if (arow >= M) arow = M - 1;
  f32x4 acc[8];
#pragma unroll
  for (int nt = 0; nt < 8; ++nt) acc[nt] = (f32x4){0.f, 0.f, 0.f, 0.f};
  const unsigned short* mr = m + (size_t)arow * HDIM + (l >> 4) * 8;
  const unsigned short* hr = h + (size_t)arow * HDIM + (l >> 4) * 8;
  const bf16x8* Wlf = (const bf16x8*)WlP;
  const bf16x8* Wrf = (const bf16x8*)WrP;
#pragma unroll
  for (int kt = 0; kt < 4; ++kt) {
    bf16x8 am = *(const bf16x8*)(mr + kt * 32);
    bf16x8 ah = *(const bf16x8*)(hr + kt * 32);
#pragma unroll
    for (int nt = 0; nt < 8; ++nt) {
      bf16x8 bl_f = Wlf[(kt * 8 + nt) * 64 + l];
      bf16x8 br_f = Wrf[(kt * 8 + nt) * 64 + l];
      acc[nt] = __builtin_amdgcn_mfma_f32_16x16x32_bf16(am, bl_f, acc[nt], 0, 0, 0);
      acc[nt] = __builtin_amdgcn_mfma_f32_16x16x32_bf16(ah, br_f, acc[nt], 0, 0, 0);
    }
  }
  int rbase = r0 + ((l >> 4) << 2);
#pragma unroll
  for (int nt = 0; nt < 8; ++nt) {
    int col = nt * 16 + (l & 15);
    float bias = bl[col];
#pragma unroll
    for (int r = 0; r < 4; ++r) {
      int row = rbase + r;
      if (row < M) out[(size_t)row * HDIM + col] = acc[nt][r] + bias;
    }
  }
}

// ---------------------------------------------------------------------------
// slot: slot[e] = running index of edge e within its dst; cnt -> degrees
// (merged histogram + slot assignment; slot written coalesced)
// ---------------------------------------------------------------------------
__global__ __launch_bounds__(256) void slot_kernel(
    const int* __restrict__ dst, int* __restrict__ cnt,
    int* __restrict__ slot, int nE) {
  int e = blockIdx.x * blockDim.x + threadIdx.x;
  if (e < nE) slot[e] = atomicAdd(&cnt[dst[e]], 1);
}

// ---------------------------------------------------------------------------
// 3-phase exclusive scan of cnt[0..n) -> off[0..n]
// ---------------------------------------------------------------------------
__global__ __launch_bounds__(1024) void scan1_kernel(
    const int* __restrict__ cnt, int* __restrict__ off,
    int* __restrict__ bsum, int n) {
  __shared__ int wsum[16];
  int i = blockIdx.x * 1024 + threadIdx.x;
  int lane = threadIdx.x & 63, wid = threadIdx.x >> 6;
  int v = (i < n) ? cnt[i] : 0;
  int x = v;
#pragma unroll
  for (int d = 1; d < 64; d <<= 1) {
    int t = __shfl_up(x, (unsigned)d, 64);
    if (lane >= d) x += t;
  }
  if (lane == 63) wsum[wid] = x;
  __syncthreads();
  if (wid == 0 && lane < 16) {
    int w = wsum[lane];
#pragma unroll
    for (int d = 1; d < 16; d <<= 1) {
      int t = __shfl_up(w, (unsigned)d, 64);
      if (lane >= d) w += t;
    }
    wsum[lane] = w;
  }
  __syncthreads();
  int wavepre = (wid == 0) ? 0 : wsum[wid - 1];
  if (i < n) off[i] = wavepre + x - v;
  if (threadIdx.x == 1023) bsum[blockIdx.x] = wavepre + x;
}

__global__ __launch_bounds__(128) void scan2_kernel(
    int* __restrict__ bsum, int* __restrict__ off, int nb, int n) {
  __shared__ int ws[2];
  int lane = threadIdx.x & 63, wid = threadIdx.x >> 6;
  int v = (threadIdx.x < nb) ? bsum[threadIdx.x] : 0;
  int x = v;
#pragma unroll
  for (int d = 1; d < 64; d <<= 1) {
    int t = __shfl_up(x, (unsigned)d, 64);
    if (lane >= d) x += t;
  }
  if (lane == 63) ws[wid] = x;
  __syncthreads();
  int pre = (wid == 0) ? 0 : ws[0];
  if (threadIdx.x < nb) bsum[threadIdx.x] = pre + x - v;  // exclusive
  if (threadIdx.x == 127) off[n] = pre + x;               // grand total
}

__global__ __launch_bounds__(256) void scan3_kernel(
    int* __restrict__ off, const int* __restrict__ bsum, int n) {
  int i = blockIdx.x * 256 + threadIdx.x;
  if (i < n) off[i] += bsum[i >> 10];
}

// ---------------------------------------------------------------------------
// fill (partitioned, atomic-free): block (chunk c, partition p) scans chunk c,
// places only edges with (dst & 15)==p -> scattered writes confined to ~1/16
// of esrc (~400 KB) so lines stay L2-hot and slot-writes combine.
// ---------------------------------------------------------------------------
__global__ __launch_bounds__(256) void fill_part_kernel(
    const int* __restrict__ src, const int* __restrict__ dst,
    const int* __restrict__ off, const int* __restrict__ slot,
    int* __restrict__ esrc, int nE) {
  int part = blockIdx.x & (NPART - 1);
  int base = (blockIdx.x >> 4) * FCHUNK;
  int endi = min(base + FCHUNK, nE);
  for (int e = base + threadIdx.x; e < endi; e += 256) {
    int d = __builtin_nontemporal_load(&dst[e]);
    if ((d & (NPART - 1)) == part) {
      int s = __builtin_nontemporal_load(&src[e]);
      int sl = __builtin_nontemporal_load(&slot[e]);
      esrc[off[d] + sl] = s;
    }
  }
}

// ---------------------------------------------------------------------------
// gather: one wave per dst row; mean of bf16 source rows -> bf16 m[row][:]
// ---------------------------------------------------------------------------
__global__ __launch_bounds__(256) void gather_kernel(
    const unsigned short* __restrict__ feat, const int* __restrict__ esrc,
    const int* __restrict__ off, unsigned short* __restrict__ m, int n_dst) {
  int w = (blockIdx.x * blockDim.x + threadIdx.x) >> 6;
  int lane = threadIdx.x & 63;
  if (w >= n_dst) return;
  int beg = off[w], end = off[w + 1];
  const unsigned* f = (const unsigned*)feat;  // row stride 64 uints
  float ax = 0.f, ay = 0.f;
  int k = beg;
  for (; k + 4 <= end; k += 4) {
    int s0 = esrc[k], s1 = esrc[k + 1], s2 = esrc[k + 2], s3 = esrc[k + 3];
    unsigned a = f[(size_t)s0 * 64 + lane];
    unsigned b = f[(size_t)s1 * 64 + lane];
    unsigned c = f[(size_t)s2 * 64 + lane];
    unsigned d = f[(size_t)s3 * 64 + lane];
    ax += b2f_lo(a) + b2f_lo(b) + b2f_lo(c) + b2f_lo(d);
    ay += b2f_hi(a) + b2f_hi(b) + b2f_hi(c) + b2f_hi(d);
  }
  for (; k < end; ++k) {
    unsigned a = f[(size_t)esrc[k] * 64 + lane];
    ax += b2f_lo(a);
    ay += b2f_hi(a);
  }
  float inv = 1.f / fmaxf((float)(end - beg), 1.f);
  unsigned o = (unsigned)f2b(ax * inv) | ((unsigned)f2b(ay * inv) << 16);
  ((unsigned*)m)[(size_t)w * 64 + lane] = o;
}

extern "C" void kernel_launch(void* const* d_in, const int* in_sizes, int n_in,
                              void* d_out, int out_size, void* d_ws, size_t ws_size,
                              hipStream_t stream) {
  const float* x_user = (const float*)d_in[0];
  const float* x_game = (const float*)d_in[1];
  const float* W_user = (const float*)d_in[2];
  const float* b_user = (const float*)d_in[3];
  const float* W_game = (const float*)d_in[4];
  const float* b_game = (const float*)d_in[5];
  const float* Wl_ug  = (const float*)d_in[6];
  const float* bl_ug  = (const float*)d_in[7];
  const float* Wr_ug  = (const float*)d_in[8];
  const float* Wl_gu  = (const float*)d_in[9];
  const float* bl_gu  = (const float*)d_in[10];
  const float* Wr_gu  = (const float*)d_in[11];
  const int*   src_ug = (const int*)d_in[12];
  const int*   dst_ug = (const int*)d_in[13];
  const int*   src_gu = (const int*)d_in[14];
  const int*   dst_gu = (const int*)d_in[15];
  const int E = in_sizes[12];

  // workspace carve (bf16 features). m_g aliases m_u.
  char* ws = (char*)d_ws;
  unsigned short* hu  = (unsigned short*)ws; ws += (size_t)NUSER * HDIM * 2;  // 25.6 MB
  unsigned short* hg  = (unsigned short*)ws; ws += (size_t)NGAME * HDIM * 2;  // 5.12 MB
  unsigned short* m_u = (unsigned short*)ws; ws += (size_t)NUSER * HDIM * 2;  // 25.6 MB
  unsigned short* m_g = m_u;
  int* esrc = (int*)ws;  ws += (size_t)E * 4;                                  // 6.4 MB
  int* slot = (int*)ws;  ws += (size_t)E * 4;                                  // 6.4 MB
  int* cnt  = (int*)ws;  ws += (size_t)NUSER * 4;
  int* off  = (int*)ws;  ws += (size_t)(NUSER + 1) * 4;
  int* bsum = (int*)ws;  ws += 256 * 4;
  unsigned short* P_wu  = (unsigned short*)ws; ws += (size_t)2 * 8 * 64 * 8 * 2;  // 16 KB
  unsigned short* P_wg  = (unsigned short*)ws; ws += (size_t)4 * 8 * 64 * 8 * 2;  // 32 KB
  unsigned short* P_lug = (unsigned short*)ws; ws += (size_t)4 * 8 * 64 * 8 * 2;
  unsigned short* P_rug = (unsigned short*)ws; ws += (size_t)4 * 8 * 64 * 8 * 2;
  unsigned short* P_lgu = (unsigned short*)ws; ws += (size_t)4 * 8 * 64 * 8 * 2;
  unsigned short* P_rgu = (unsigned short*)ws; ws += (size_t)4 * 8 * 64 * 8 * 2;

  float* out_user = (float*)d_out;
  float* out_game = (float*)d_out + (size_t)NUSER * HDIM;

  const int eb = (E + 255) / 256;
  const int fb = ((E + FCHUNK - 1) / FCHUNK) * NPART;

  // one-shot weight repack to MFMA fragment order (bf16)
  repack_kernel<<<dim3(8, 6), 256, 0, stream>>>(
      W_user, W_game, Wl_ug, Wr_ug, Wl_gu, Wr_gu,
      P_wu, P_wg, P_lug, P_rug, P_lgu, P_rgu);

  // input projections + relu (bf16 out)
  proj_mfma_kernel<64><<<(NUSER + 63) / 64, 256, 0, stream>>>(x_user, P_wu, b_user, hu, NUSER);
  proj_mfma_kernel<128><<<(NGAME + 63) / 64, 256, 0, stream>>>(x_game, P_wg, b_game, hg, NGAME);

  // ---- relation user->game (dst = games) ----
  {
    const int n = NGAME, nb = (n + 1023) / 1024;
    hipMemsetAsync(cnt, 0, (size_t)n * 4, stream);
    slot_kernel<<<eb, 256, 0, stream>>>(dst_ug, cnt, slot, E);
    scan1_kernel<<<nb, 1024, 0, stream>>>(cnt, off, bsum, n);
    scan2_kernel<<<1, 128, 0, stream>>>(bsum, off, nb, n);
    scan3_kernel<<<(n + 255) / 256, 256, 0, stream>>>(off, bsum, n);
    fill_part_kernel<<<fb, 256, 0, stream>>>(src_ug, dst_ug, off, slot, esrc, E);
    gather_kernel<<<(n * 64 + 255) / 256, 256, 0, stream>>>(hu, esrc, off, m_g, n);
    out_mfma_kernel<<<(n + 63) / 64, 256, 0, stream>>>(m_g, hg, P_lug, bl_ug, P_rug, out_game, n);
  }

  // ---- relation game->user (dst = users) ----
  {
    const int n = NUSER, nb = (n + 1023) / 1024;
    hipMemsetAsync(cnt, 0, (size_t)n * 4, stream);
    slot_kernel<<<eb, 256, 0, stream>>>(dst_gu, cnt, slot, E);
    scan1_kernel<<<nb, 1024, 0, stream>>>(cnt, off, bsum, n);
    scan2_kernel<<<1, 128, 0, stream>>>(bsum, off, nb, n);
    scan3_kernel<<<(n + 255) / 256, 256, 0, stream>>>(off, bsum, n);
    fill_part_kernel<<<fb, 256, 0, stream>>>(src_gu, dst_gu, off, slot, esrc, E);
    gather_kernel<<<(n * 64 + 255) / 256, 256, 0, stream>>>(hg, esrc, off, m_u, n);
    out_mfma_kernel<<<(n + 63) / 64, 256, 0, stream>>>(m_u, hu, P_lgu, bl_gu, P_rgu, out_user, n);
  }
}

// Round 6
// 426.673 us; speedup vs baseline: 15.6947x; 1.2362x over previous
//
#include <hip/hip_runtime.h>
#include <hip/hip_bf16.h>

#define NUSER 100000
#define NGAME 20000
#define NTOT  120000   // NGAME + NUSER (games first in combined index space)
#define HDIM  128
#define NPART 16
#define FCHUNK 4096

typedef short bf16x8 __attribute__((ext_vector_type(8)));
typedef float f32x4  __attribute__((ext_vector_type(4)));

__device__ __forceinline__ unsigned short f2b(float f) {
  union { float f; unsigned u; } a;
  a.f = f;
  unsigned r = a.u + 0x7fff + ((a.u >> 16) & 1);  // RNE
  return (unsigned short)(r >> 16);
}
__device__ __forceinline__ float b2f_lo(unsigned u) {
  union { unsigned u; float f; } a; a.u = u << 16; return a.f;
}
__device__ __forceinline__ float b2f_hi(unsigned u) {
  union { unsigned u; float f; } a; a.u = u & 0xffff0000u; return a.f;
}

// ---------------------------------------------------------------------------
// repack: W[K][128] f32 -> fragment-ordered bf16 for mfma_f32_16x16x32_bf16
// ---------------------------------------------------------------------------
__global__ __launch_bounds__(256) void repack_kernel(
    const float* __restrict__ W0, const float* __restrict__ W1,
    const float* __restrict__ W2, const float* __restrict__ W3,
    const float* __restrict__ W4, const float* __restrict__ W5,
    unsigned short* __restrict__ P0, unsigned short* __restrict__ P1,
    unsigned short* __restrict__ P2, unsigned short* __restrict__ P3,
    unsigned short* __restrict__ P4, unsigned short* __restrict__ P5) {
  const float* W; unsigned short* P; int K;
  switch (blockIdx.y) {
    case 0: W = W0; P = P0; K = 64;  break;
    case 1: W = W1; P = P1; K = 128; break;
    case 2: W = W2; P = P2; K = 128; break;
    case 3: W = W3; P = P3; K = 128; break;
    case 4: W = W4; P = P4; K = 128; break;
    default: W = W5; P = P5; K = 128; break;
  }
  int t = blockIdx.x * 256 + threadIdx.x;
  int KT = K / 32;
  if (t >= KT * 8 * 64) return;
  int lane = t & 63;
  int nt = (t >> 6) & 7;
  int kt = t >> 9;
  int col = nt * 16 + (lane & 15);
  int krow = kt * 32 + (lane >> 4) * 8;
  unsigned short vals[8];
#pragma unroll
  for (int b = 0; b < 8; ++b) vals[b] = f2b(W[(size_t)(krow + b) * HDIM + col]);
  *reinterpret_cast<bf16x8*>(P + (size_t)t * 8) = *reinterpret_cast<bf16x8*>(vals);
}

// ---------------------------------------------------------------------------
// proj_mfma: h = relu(x @ W + b), x f32 [M][K], W prepacked bf16, h bf16 [M][128]
// ---------------------------------------------------------------------------
template <int K>
__global__ __launch_bounds__(256) void proj_mfma_kernel(
    const float* __restrict__ x, const unsigned short* __restrict__ Wp,
    const float* __restrict__ b, unsigned short* __restrict__ h, int M) {
  int l = threadIdx.x & 63;
  int wid = threadIdx.x >> 6;
  int r0 = blockIdx.x * 64 + wid * 16;
  int arow = r0 + (l & 15);
  if (arow >= M) arow = M - 1;
  const int KT = K / 32;
  f32x4 acc[8];
#pragma unroll
  for (int nt = 0; nt < 8; ++nt) acc[nt] = (f32x4){0.f, 0.f, 0.f, 0.f};
  const float* xr = x + (size_t)arow * K + (l >> 4) * 8;
  const bf16x8* Wf = (const bf16x8*)Wp;
#pragma unroll
  for (int kt = 0; kt < KT; ++kt) {
    float4 a0 = *(const float4*)(xr + kt * 32);
    float4 a1 = *(const float4*)(xr + kt * 32 + 4);
    bf16x8 af;
    af[0] = (short)f2b(a0.x); af[1] = (short)f2b(a0.y);
    af[2] = (short)f2b(a0.z); af[3] = (short)f2b(a0.w);
    af[4] = (short)f2b(a1.x); af[5] = (short)f2b(a1.y);
    af[6] = (short)f2b(a1.z); af[7] = (short)f2b(a1.w);
#pragma unroll
    for (int nt = 0; nt < 8; ++nt) {
      bf16x8 bf = Wf[(kt * 8 + nt) * 64 + l];
      acc[nt] = __builtin_amdgcn_mfma_f32_16x16x32_bf16(af, bf, acc[nt], 0, 0, 0);
    }
  }
  int rbase = r0 + ((l >> 4) << 2);
#pragma unroll
  for (int nt = 0; nt < 8; ++nt) {
    int col = nt * 16 + (l & 15);
    float bias = b[col];
#pragma unroll
    for (int r = 0; r < 4; ++r) {
      int row = rbase + r;
      if (row < M) h[(size_t)row * HDIM + col] = f2b(fmaxf(acc[nt][r] + bias, 0.f));
    }
  }
}

// ---------------------------------------------------------------------------
// out_mfma_fused: both relations in one launch.
// blocks [0, GB): games:  out_game = m[0:NG] @ P_lug + hg @ P_rug + bl_ug
// blocks [GB,..): users:  out_user = m[NG:]  @ P_lgu + hu @ P_rgu + bl_gu
// ---------------------------------------------------------------------------
#define GB ((NGAME + 63) / 64)
#define UB ((NUSER + 63) / 64)
__global__ __launch_bounds__(256) void out_mfma_fused_kernel(
    const unsigned short* __restrict__ m, const unsigned short* __restrict__ hg,
    const unsigned short* __restrict__ hu,
    const unsigned short* __restrict__ P_lug, const float* __restrict__ bl_ug,
    const unsigned short* __restrict__ P_rug,
    const unsigned short* __restrict__ P_lgu, const float* __restrict__ bl_gu,
    const unsigned short* __restrict__ P_rgu,
    float* __restrict__ out_game, float* __restrict__ out_user) {
  const unsigned short *mb, *h, *WlP, *WrP;
  const float* bl;
  float* out;
  int M, bi;
  if (blockIdx.x < GB) {
    mb = m;                          h = hg; WlP = P_lug; bl = bl_ug; WrP = P_rug;
    out = out_game; M = NGAME; bi = blockIdx.x;
  } else {
    mb = m + (size_t)NGAME * HDIM;   h = hu; WlP = P_lgu; bl = bl_gu; WrP = P_rgu;
    out = out_user; M = NUSER; bi = blockIdx.x - GB;
  }
  int l = threadIdx.x & 63;
  int wid = threadIdx.x >> 6;
  int r0 = bi * 64 + wid * 16;
  int arow = r0 + (l & 15);
  if (arow >= M) arow = M - 1;
  f32x4 acc[8];
#pragma unroll
  for (int nt = 0; nt < 8; ++nt) acc[nt] = (f32x4){0.f, 0.f, 0.f, 0.f};
  const unsigned short* mr = mb + (size_t)arow * HDIM + (l >> 4) * 8;
  const unsigned short* hr = h + (size_t)arow * HDIM + (l >> 4) * 8;
  const bf16x8* Wlf = (const bf16x8*)WlP;
  const bf16x8* Wrf = (const bf16x8*)WrP;
#pragma unroll
  for (int kt = 0; kt < 4; ++kt) {
    bf16x8 am = *(const bf16x8*)(mr + kt * 32);
    bf16x8 ah = *(const bf16x8*)(hr + kt * 32);
#pragma unroll
    for (int nt = 0; nt < 8; ++nt) {
      bf16x8 bl_f = Wlf[(kt * 8 + nt) * 64 + l];
      bf16x8 br_f = Wrf[(kt * 8 + nt) * 64 + l];
      acc[nt] = __builtin_amdgcn_mfma_f32_16x16x32_bf16(am, bl_f, acc[nt], 0, 0, 0);
      acc[nt] = __builtin_amdgcn_mfma_f32_16x16x32_bf16(ah, br_f, acc[nt], 0, 0, 0);
    }
  }
  int rbase = r0 + ((l >> 4) << 2);
#pragma unroll
  for (int nt = 0; nt < 8; ++nt) {
    int col = nt * 16 + (l & 15);
    float bias = bl[col];
#pragma unroll
    for (int r = 0; r < 4; ++r) {
      int row = rbase + r;
      if (row < M) out[(size_t)row * HDIM + col] = acc[nt][r] + bias;
    }
  }
}

// ---------------------------------------------------------------------------
// slot (combined): e<E -> relation ug (dst=game idx d), e>=E -> gu (dst=NGAME+d)
// ---------------------------------------------------------------------------
__global__ __launch_bounds__(256) void slot_kernel(
    const int* __restrict__ dst_ug, const int* __restrict__ dst_gu,
    int* __restrict__ cnt, int* __restrict__ slot, int E) {
  int e = blockIdx.x * blockDim.x + threadIdx.x;
  if (e >= 2 * E) return;
  int d = (e < E) ? dst_ug[e] : (NGAME + dst_gu[e - E]);
  slot[e] = atomicAdd(&cnt[d], 1);
}

// ---------------------------------------------------------------------------
// 3-phase exclusive scan of cnt[0..n) -> off[0..n]
// ---------------------------------------------------------------------------
__global__ __launch_bounds__(1024) void scan1_kernel(
    const int* __restrict__ cnt, int* __restrict__ off,
    int* __restrict__ bsum, int n) {
  __shared__ int wsum[16];
  int i = blockIdx.x * 1024 + threadIdx.x;
  int lane = threadIdx.x & 63, wid = threadIdx.x >> 6;
  int v = (i < n) ? cnt[i] : 0;
  int x = v;
#pragma unroll
  for (int d = 1; d < 64; d <<= 1) {
    int t = __shfl_up(x, (unsigned)d, 64);
    if (lane >= d) x += t;
  }
  if (lane == 63) wsum[wid] = x;
  __syncthreads();
  if (wid == 0 && lane < 16) {
    int w = wsum[lane];
#pragma unroll
    for (int d = 1; d < 16; d <<= 1) {
      int t = __shfl_up(w, (unsigned)d, 64);
      if (lane >= d) w += t;
    }
    wsum[lane] = w;
  }
  __syncthreads();
  int wavepre = (wid == 0) ? 0 : wsum[wid - 1];
  if (i < n) off[i] = wavepre + x - v;
  if (threadIdx.x == 1023) bsum[blockIdx.x] = wavepre + x;
}

__global__ __launch_bounds__(128) void scan2_kernel(
    int* __restrict__ bsum, int* __restrict__ off, int nb, int n) {
  __shared__ int ws[2];
  int lane = threadIdx.x & 63, wid = threadIdx.x >> 6;
  int v = (threadIdx.x < nb) ? bsum[threadIdx.x] : 0;
  int x = v;
#pragma unroll
  for (int d = 1; d < 64; d <<= 1) {
    int t = __shfl_up(x, (unsigned)d, 64);
    if (lane >= d) x += t;
  }
  if (lane == 63) ws[wid] = x;
  __syncthreads();
  int pre = (wid == 0) ? 0 : ws[0];
  if (threadIdx.x < nb) bsum[threadIdx.x] = pre + x - v;  // exclusive
  if (threadIdx.x == 127) off[n] = pre + x;               // grand total
}

__global__ __launch_bounds__(256) void scan3_kernel(
    int* __restrict__ off, const int* __restrict__ bsum, int n) {
  int i = blockIdx.x * 256 + threadIdx.x;
  if (i < n) off[i] += bsum[i >> 10];
}

// ---------------------------------------------------------------------------
// fill (combined, partitioned, atomic-free). Cached (L3-served) re-reads.
// ---------------------------------------------------------------------------
__global__ __launch_bounds__(256) void fill_part_kernel(
    const int* __restrict__ src_ug, const int* __restrict__ dst_ug,
    const int* __restrict__ src_gu, const int* __restrict__ dst_gu,
    const int* __restrict__ off, const int* __restrict__ slot,
    int* __restrict__ esrc, int E) {
  int part = blockIdx.x & (NPART - 1);
  int base = (blockIdx.x >> 4) * FCHUNK;
  int endi = min(base + FCHUNK, 2 * E);
  for (int e = base + threadIdx.x; e < endi; e += 256) {
    int d = (e < E) ? dst_ug[e] : (NGAME + dst_gu[e - E]);
    if ((d & (NPART - 1)) == part) {
      int s = (e < E) ? src_ug[e] : src_gu[e - E];
      esrc[off[d] + slot[e]] = s;
    }
  }
}

// ---------------------------------------------------------------------------
// gather (combined): rows [0,NGAME) read hu; rows [NGAME,NTOT) read hg.
// one wave per dst row; mean of bf16 source rows -> bf16 m[row][:]
// ---------------------------------------------------------------------------
__global__ __launch_bounds__(256) void gather_kernel(
    const unsigned short* __restrict__ hu, const unsigned short* __restrict__ hg,
    const int* __restrict__ esrc, const int* __restrict__ off,
    unsigned short* __restrict__ m) {
  int w = (blockIdx.x * blockDim.x + threadIdx.x) >> 6;
  int lane = threadIdx.x & 63;
  if (w >= NTOT) return;
  int beg = off[w], end = off[w + 1];
  const unsigned* f = (const unsigned*)((w < NGAME) ? hu : hg);  // row stride 64 uints
  float ax = 0.f, ay = 0.f;
  int k = beg;
  for (; k + 4 <= end; k += 4) {
    int s0 = esrc[k], s1 = esrc[k + 1], s2 = esrc[k + 2], s3 = esrc[k + 3];
    unsigned a = f[(size_t)s0 * 64 + lane];
    unsigned b = f[(size_t)s1 * 64 + lane];
    unsigned c = f[(size_t)s2 * 64 + lane];
    unsigned d = f[(size_t)s3 * 64 + lane];
    ax += b2f_lo(a) + b2f_lo(b) + b2f_lo(c) + b2f_lo(d);
    ay += b2f_hi(a) + b2f_hi(b) + b2f_hi(c) + b2f_hi(d);
  }
  for (; k < end; ++k) {
    unsigned a = f[(size_t)esrc[k] * 64 + lane];
    ax += b2f_lo(a);
    ay += b2f_hi(a);
  }
  float inv = 1.f / fmaxf((float)(end - beg), 1.f);
  unsigned o = (unsigned)f2b(ax * inv) | ((unsigned)f2b(ay * inv) << 16);
  ((unsigned*)m)[(size_t)w * 64 + lane] = o;
}

extern "C" void kernel_launch(void* const* d_in, const int* in_sizes, int n_in,
                              void* d_out, int out_size, void* d_ws, size_t ws_size,
                              hipStream_t stream) {
  const float* x_user = (const float*)d_in[0];
  const float* x_game = (const float*)d_in[1];
  const float* W_user = (const float*)d_in[2];
  const float* b_user = (const float*)d_in[3];
  const float* W_game = (const float*)d_in[4];
  const float* b_game = (const float*)d_in[5];
  const float* Wl_ug  = (const float*)d_in[6];
  const float* bl_ug  = (const float*)d_in[7];
  const float* Wr_ug  = (const float*)d_in[8];
  const float* Wl_gu  = (const float*)d_in[9];
  const float* bl_gu  = (const float*)d_in[10];
  const float* Wr_gu  = (const float*)d_in[11];
  const int*   src_ug = (const int*)d_in[12];
  const int*   dst_ug = (const int*)d_in[13];
  const int*   src_gu = (const int*)d_in[14];
  const int*   dst_gu = (const int*)d_in[15];
  const int E = in_sizes[12];

  // workspace carve (bf16 features); combined CSR over NTOT dst nodes
  char* ws = (char*)d_ws;
  unsigned short* hu  = (unsigned short*)ws; ws += (size_t)NUSER * HDIM * 2;  // 25.6 MB
  unsigned short* hg  = (unsigned short*)ws; ws += (size_t)NGAME * HDIM * 2;  // 5.12 MB
  unsigned short* m   = (unsigned short*)ws; ws += (size_t)NTOT * HDIM * 2;   // 30.7 MB
  int* esrc = (int*)ws;  ws += (size_t)2 * E * 4;                              // 12.8 MB
  int* slot = (int*)ws;  ws += (size_t)2 * E * 4;                              // 12.8 MB
  int* cnt  = (int*)ws;  ws += (size_t)NTOT * 4;
  int* off  = (int*)ws;  ws += (size_t)(NTOT + 1) * 4;
  int* bsum = (int*)ws;  ws += 256 * 4;
  unsigned short* P_wu  = (unsigned short*)ws; ws += (size_t)2 * 8 * 64 * 8 * 2;  // 16 KB
  unsigned short* P_wg  = (unsigned short*)ws; ws += (size_t)4 * 8 * 64 * 8 * 2;  // 32 KB
  unsigned short* P_lug = (unsigned short*)ws; ws += (size_t)4 * 8 * 64 * 8 * 2;
  unsigned short* P_rug = (unsigned short*)ws; ws += (size_t)4 * 8 * 64 * 8 * 2;
  unsigned short* P_lgu = (unsigned short*)ws; ws += (size_t)4 * 8 * 64 * 8 * 2;
  unsigned short* P_rgu = (unsigned short*)ws; ws += (size_t)4 * 8 * 64 * 8 * 2;

  float* out_user = (float*)d_out;
  float* out_game = (float*)d_out + (size_t)NUSER * HDIM;

  const int n = NTOT, nb = (n + 1023) / 1024;
  const int fb = ((2 * E + FCHUNK - 1) / FCHUNK) * NPART;

  // one-shot weight repack to MFMA fragment order (bf16)
  repack_kernel<<<dim3(8, 6), 256, 0, stream>>>(
      W_user, W_game, Wl_ug, Wr_ug, Wl_gu, Wr_gu,
      P_wu, P_wg, P_lug, P_rug, P_lgu, P_rgu);

  // input projections + relu (bf16 out)
  proj_mfma_kernel<64><<<(NUSER + 63) / 64, 256, 0, stream>>>(x_user, P_wu, b_user, hu, NUSER);
  proj_mfma_kernel<128><<<(NGAME + 63) / 64, 256, 0, stream>>>(x_game, P_wg, b_game, hg, NGAME);

  // combined CSR build over both relations
  hipMemsetAsync(cnt, 0, (size_t)n * 4, stream);
  slot_kernel<<<(2 * E + 255) / 256, 256, 0, stream>>>(dst_ug, dst_gu, cnt, slot, E);
  scan1_kernel<<<nb, 1024, 0, stream>>>(cnt, off, bsum, n);
  scan2_kernel<<<1, 128, 0, stream>>>(bsum, off, nb, n);
  scan3_kernel<<<(n + 255) / 256, 256, 0, stream>>>(off, bsum, n);
  fill_part_kernel<<<fb, 256, 0, stream>>>(src_ug, dst_ug, src_gu, dst_gu, off, slot, esrc, E);

  // combined gather (means for both relations)
  gather_kernel<<<(NTOT * 64 + 255) / 256, 256, 0, stream>>>(hu, hg, esrc, off, m);

  // fused output projections
  out_mfma_fused_kernel<<<GB + UB, 256, 0, stream>>>(
      m, hg, hu, P_lug, bl_ug, P_rug, P_lgu, bl_gu, P_rgu, out_game, out_user);
}